// Round 1
// baseline (320.058 us; speedup 1.0000x reference)
//
#include <hip/hip_runtime.h>
#include <math.h>

#define C_DIM 2048
#define E_DIM 64
#define KC    128
#define TM    32     // tokens per block (K1)
#define TW    8      // tokens per wave (K1)

// ---------------- K1: logits (fp64-accurate) + top-2 + softmax ----------------
__launch_bounds__(256)
__global__ void k_logits_top2(const float* __restrict__ x, const float* __restrict__ w,
                              int* __restrict__ idx0, int* __restrict__ idx1,
                              float* __restrict__ probs, int N)
{
    __shared__ float xs[TM][KC];            // 16 KB
    __shared__ float wsh[E_DIM][KC + 4];    // 33 KB, +4 pad breaks b128 lane conflicts

    const int tid  = threadIdx.x;
    const int lane = tid & 63;
    const int wid  = tid >> 6;
    const int t0   = blockIdx.x * TM;

    double acc[TW];
#pragma unroll
    for (int t = 0; t < TW; ++t) acc[t] = 0.0;

    for (int kb = 0; kb < C_DIM; kb += KC) {
        __syncthreads();
        // stage x tile: 32 rows x 128 floats = 1024 float4, 4 per thread
#pragma unroll
        for (int r = 0; r < 4; ++r) {
            int i = tid + 256 * r;
            int row = i >> 5;
            int col = i & 31;
            float4 v = *(const float4*)(x + (size_t)(t0 + row) * C_DIM + kb + col * 4);
            *(float4*)(&xs[row][col * 4]) = v;
        }
        // stage w tile (transposed layout [e][k]): 64 rows x 128 floats, 8 f4/thread
#pragma unroll
        for (int r = 0; r < 8; ++r) {
            int i = tid + 256 * r;
            int row = i >> 5;
            int col = i & 31;
            float4 v = *(const float4*)(w + (size_t)row * C_DIM + kb + col * 4);
            *(float4*)(&wsh[row][col * 4]) = v;
        }
        __syncthreads();

        const int tw = wid * TW;
        for (int k = 0; k < KC; k += 4) {
            const float4 wv = *(const float4*)(&wsh[lane][k]);
#pragma unroll
            for (int t = 0; t < TW; ++t) {
                const float4 xv = *(const float4*)(&xs[tw + t][k]);
                // 4-element fp32 sub-dot (error ~eps*|local|), then fp64 accumulate:
                // ordering accuracy ~5e-8 absolute, matches fp64 reference ordering.
                float s = fmaf(xv.x, wv.x, fmaf(xv.y, wv.y, fmaf(xv.z, wv.z, xv.w * wv.w)));
                acc[t] += (double)s;
            }
        }
    }

    // per-token top-2 across the 64 lanes (lane == expert). Lower index wins ties
    // (matches jax.lax.top_k).
    const int tw = wid * TW;
#pragma unroll
    for (int t = 0; t < TW; ++t) {
        double v = acc[t];
        int ix = lane;
#pragma unroll
        for (int off = 32; off > 0; off >>= 1) {
            double ov = __shfl_down(v, off, 64);
            int    oi = __shfl_down(ix, off, 64);
            if (ov > v || (ov == v && oi < ix)) { v = ov; ix = oi; }
        }
        int    i1 = __shfl(ix, 0, 64);
        double v1 = __shfl(v, 0, 64);

        v  = (lane == i1) ? -1e300 : acc[t];
        ix = lane;
#pragma unroll
        for (int off = 32; off > 0; off >>= 1) {
            double ov = __shfl_down(v, off, 64);
            int    oi = __shfl_down(ix, off, 64);
            if (ov > v || (ov == v && oi < ix)) { v = ov; ix = oi; }
        }
        int    i2 = __shfl(ix, 0, 64);
        double v2 = __shfl(v, 0, 64);

        if (lane == 0) {
            int n = t0 + tw + t;
            double p0 = 1.0 / (1.0 + exp(v2 - v1));   // stable: v2 <= v1
            idx0[n] = i1;
            idx1[n] = i2;
            probs[2 * n]     = (float)p0;
            probs[2 * n + 1] = (float)(1.0 - p0);
        }
    }
}

// ---------------- K2: per-expert deterministic rank scan ----------------
// block e computes, in k-major token order, the exclusive running count of
// tokens selecting expert e; k=1 ranks continue from the k=0 total.
__launch_bounds__(256)
__global__ void k_scan(const int* __restrict__ idx0, const int* __restrict__ idx1,
                       int* __restrict__ r0, int* __restrict__ r1, int N)
{
    const int e    = blockIdx.x;
    const int tid  = threadIdx.x;
    const int lane = tid & 63;
    const int wid  = tid >> 6;
    __shared__ int wsum[4];

    int running = 0;   // every thread tracks the same value
    const unsigned long long ltmask = (1ull << lane) - 1ull;

    for (int pass = 0; pass < 2; ++pass) {
        const int* idx = pass ? idx1 : idx0;
        int*       r   = pass ? r1   : r0;
        for (int base = 0; base < N; base += 256 * 4) {
            int v[4];
#pragma unroll
            for (int j = 0; j < 4; ++j) v[j] = idx[base + j * 256 + tid];
#pragma unroll
            for (int j = 0; j < 4; ++j) {
                bool p = (v[j] == e);
                unsigned long long b = __ballot(p);
                int prefix = __popcll(b & ltmask);
                if (lane == 0) wsum[wid] = __popcll(b);
                __syncthreads();
                int woff = 0, total = 0;
#pragma unroll
                for (int w2 = 0; w2 < 4; ++w2) {
                    int s = wsum[w2];
                    total += s;
                    if (w2 < wid) woff += s;
                }
                if (p) r[base + j * 256 + tid] = running + woff + prefix;
                running += total;
                __syncthreads();
            }
        }
    }
}

// ---------------- K3: one-hot capacity mask fill (float4-coalesced) ----------------
__launch_bounds__(256)
__global__ void k_mask(const int* __restrict__ idx0, const int* __restrict__ idx1,
                       const int* __restrict__ r0, const int* __restrict__ r1,
                       float* __restrict__ out, int N, int cap)
{
    int f = blockIdx.x * blockDim.x + threadIdx.x;   // float4 index, total N*32
    int n   = f >> 5;
    int rem = (f & 31) * 4;       // 0..124 within the token's 128 floats
    int k   = rem >> 6;           // 0 or 1
    int e0  = rem & 63;           // first of 4 experts this f4 covers
    int ix = k ? idx1[n] : idx0[n];
    int rr = k ? r1[n]   : r0[n];
    float val = (rr < cap) ? 1.0f : 0.0f;
    float4 o = make_float4(0.f, 0.f, 0.f, 0.f);
    int d = ix - e0;
    if (d >= 0 && d < 4) ((float*)&o)[d] = val;
    *(float4*)(out + (size_t)f * 4) = o;
}

// ---------------- K4: probs_masked / indices / final_rank / capacity ----------------
__launch_bounds__(256)
__global__ void k_tail(const int* __restrict__ idx0, const int* __restrict__ idx1,
                       const int* __restrict__ r0, const int* __restrict__ r1,
                       const float* __restrict__ probs,
                       float* __restrict__ out, int N, int cap)
{
    int i = blockIdx.x * blockDim.x + threadIdx.x;   // 0 .. 2N-1
    size_t base = (size_t)2 * N * E_DIM;
    if (i < 2 * N) {
        int n = i >> 1;
        int k = i & 1;
        int ix = k ? idx1[n] : idx0[n];
        int rr = k ? r1[n]   : r0[n];
        float p = probs[i];
        bool keep = (rr < cap);
        out[base + i]             = keep ? p : 0.0f;   // router_probs_masked
        out[base + 2 * N + i]     = (float)ix;         // top_k_indices
        out[base + 4 * N + i]     = (float)rr;         // final_rank
    }
    if (i == 0) out[base + 6 * N] = (float)cap;        // exp_capacity
}

extern "C" void kernel_launch(void* const* d_in, const int* in_sizes, int n_in,
                              void* d_out, int out_size, void* d_ws, size_t ws_size,
                              hipStream_t stream)
{
    const float* x  = (const float*)d_in[0];
    const float* wg = (const float*)d_in[1];
    const int N = in_sizes[0] / C_DIM;   // 16384 tokens

    // workspace layout (24*N bytes total = 384 KB)
    char* ws = (char*)d_ws;
    int*   idx0  = (int*)ws;
    int*   idx1  = idx0 + N;
    float* probs = (float*)(idx1 + N);
    int*   r0    = (int*)(probs + 2 * N);
    int*   r1    = r0 + N;

    float* out = (float*)d_out;

    int cap = (int)((long long)2 * 2 * N / E_DIM);   // TOP_K * EVAL_CAPACITY * N / E
    if (cap < 4) cap = 4;

    k_logits_top2<<<N / TM, 256, 0, stream>>>(x, wg, idx0, idx1, probs, N);
    k_scan<<<E_DIM, 256, 0, stream>>>(idx0, idx1, r0, r1, N);
    k_mask<<<(N * 32) / 256, 256, 0, stream>>>(idx0, idx1, r0, r1, out, N, cap);
    k_tail<<<(2 * N + 255) / 256, 256, 0, stream>>>(idx0, idx1, r0, r1, probs, out, N, cap);
}